// Round 1
// 91.063 us; speedup vs baseline: 1.0444x; 1.0444x over previous
//
#include <hip/hip_runtime.h>

// ADSR envelope. B=64 voices x T=131072 samples. Output f32.
//
// Closed form per row given th = number of leading ones in gate:
//   t+1 <= attack          : (t+1)/attack
//   t <  th (decay)        : sustain + (1-sustain)*exp(-(t+1-attack)/decay)
//   t >= th (release)      : R * exp(-(t-th+1)/release),
//                            R = sustain + (1-sustain)*exp(-(th+1-attack)/decay)
//
// v2: block-shared threshold search.
//  - gate rows are monotone (prefix of ones), so a block whose LAST covered
//    sample is still 1 is entirely pre-threshold -> skip the search (one
//    broadcast load). ~50% of blocks take this path (th in [T/4, 3T/4)).
//  - Otherwise only WAVE 0 runs the 3-round 64-ary ballot search
//    (steps 2048/32/1; invariant th-1 in (a, a+S]) and broadcasts th via LDS.
//  - Cuts scattered L2 probe transactions ~6-8x vs the previous
//    every-wave-searches version (32768 searching waves -> ~4-6K).
// Single dispatch; HBM traffic ~= 32 MB write only (probes are L2-hot).

#define T_LEN   131072          // 2^17
#define T_LOG2  17

__global__ __launch_bounds__(256) void adsr_fused(
        const float* __restrict__ gate,
        const float* __restrict__ attack_p,
        const float* __restrict__ decay_p,
        const float* __restrict__ sustain_p,
        const float* __restrict__ release_p,
        float*       __restrict__ out) {
    __shared__ int s_th;

    const int row  = blockIdx.x >> 7;                 // 128 blocks per row
    const int tblk = (blockIdx.x & 127) << 10;        // block covers [tblk, tblk+1024)
    const float* grow = gate + (size_t)row * T_LEN;

    if (threadIdx.x < 64) {                           // wave 0 only
        const int lane = threadIdx.x;
        int th = 0x7fffffff;                          // sentinel: "beyond this block"
        // Broadcast load (all lanes same address, L2-hot). If the last sample
        // of this block is gated on, every t in the block satisfies t < th.
        if (!(grow[tblk + 1023] > 0.5f)) {
            int a = -1;
            {
                int p = a + (lane + 1) * 2048;        // covers 2047..131071
                unsigned long long m = __ballot(grow[p] > 0.5f);
                a += (int)__popcll(m) * 2048;
            }
            {
                int p = a + (lane + 1) * 32;
                unsigned long long m = __ballot(grow[p] > 0.5f);
                a += (int)__popcll(m) * 32;
            }
            {
                int p = a + (lane + 1);               // probes past window read 0s — harmless
                unsigned long long m = __ballot(grow[p] > 0.5f);
                a += (int)__popcll(m);
            }
            th = a + 1;
        }
        if (lane == 0) s_th = th;
    }
    __syncthreads();
    const int th = s_th;

    // --- closed-form envelope ---
    const float attack  = *attack_p;
    const float decay   = *decay_p;
    const float sustain = *sustain_p;
    const float release = *release_p;

    const float inv_attack   = 1.0f / attack;
    const float ninv_decay   = -1.0f / decay;
    const float ninv_release = -1.0f / release;
    const float one_ms       = 1.0f - sustain;

    // release start level (decay continued one extra step past th-1).
    // th may be the INT_MAX sentinel: __expf(huge negative) -> 0, R unused then.
    const float R = sustain + one_ms * __expf(((float)th + 1.0f - attack) * ninv_decay);

    const int idx4 = blockIdx.x * 256 + threadIdx.x;  // float4 index, contiguous
    const int t0   = (idx4 & ((T_LEN / 4) - 1)) << 2;

    float4 o;
    float* op = &o.x;
    #pragma unroll
    for (int j = 0; j < 4; ++j) {
        int t = t0 + j;
        float val;
        if (t < th) {
            float x = (float)(t + 1);
            val = (x <= attack) ? x * inv_attack
                                : sustain + one_ms * __expf((x - attack) * ninv_decay);
        } else {
            val = R * __expf((float)(t - th + 1) * ninv_release);
        }
        op[j] = val;
    }
    ((float4*)out)[idx4] = o;
}

extern "C" void kernel_launch(void* const* d_in, const int* in_sizes, int n_in,
                              void* d_out, int out_size, void* d_ws, size_t ws_size,
                              hipStream_t stream) {
    const float* gate    = (const float*)d_in[0];
    const float* attack  = (const float*)d_in[1];
    const float* decay   = (const float*)d_in[2];
    const float* sustain = (const float*)d_in[3];
    const float* release = (const float*)d_in[4];
    float* out = (float*)d_out;

    const int B = in_sizes[0] / T_LEN;               // 64
    const int total_f4 = (B * T_LEN) / 4;            // 2,097,152
    adsr_fused<<<total_f4 / 256, 256, 0, stream>>>(
        gate, attack, decay, sustain, release, out);
}